// Round 7
// baseline (101953.601 us; speedup 1.0000x reference)
//
#include <hip/hip_runtime.h>
#include <hip/hip_fp16.h>
#include <math.h>

// Problem constants
#define BATCH 256
#define TSEQ  512
#define FEAT  64
#define NU1   256
#define NU2   128

// half2-element offsets inside workspace (packed fp16 weight planes)
// Pair-plane layout (R2-proven, L2-resident): plane[pair][col], half2=(row0,row0+1).
// GRU1: 160 pairs (64 x-rows then 256 h-rows) x 256 cols, per gate.
// GRU2: 192 pairs (256 h1-rows then 128 h2-rows) x 128 cols, per gate.
#define G1Z_OFF 0
#define G1R_OFF 40960
#define G1H_OFF 81920
#define G2Z_OFF 122880
#define G2R_OFF 147456
#define G2H_OFF 172032
#define TOTAL_H2 196608   // 786,432 bytes of d_ws

__device__ __forceinline__ float sigmoid_f(float v) {
    return 1.0f / (1.0f + __expf(-v));
}
__device__ __forceinline__ float tanh_f(float v) {
    float c = fminf(fmaxf(v, -15.0f), 15.0f);
    float e = __expf(2.0f * c);
    return (e - 1.0f) / (e + 1.0f);
}

// ---------------- weight packing (fp32 -> fp16 pair planes) ----------------
__global__ void pack_weights(const float* __restrict__ k1, const float* __restrict__ r1,
                             const float* __restrict__ k2, const float* __restrict__ r2,
                             __half2* __restrict__ ws)
{
    int idx = blockIdx.x * 256 + threadIdx.x;
    if (idx >= TOTAL_H2) return;
    float a, b;
    if (idx < G2Z_OFF) {
        int plane = idx / 40960;       // 0=z 1=r 2=h
        int rem   = idx % 40960;
        int pair  = rem >> 8;
        int col   = rem & 255;
        int g     = plane * 256 + col;
        int row0  = pair * 2;
        if (row0 < 64) { a = k1[row0 * 768 + g];        b = k1[(row0 + 1) * 768 + g]; }
        else           { a = r1[(row0 - 64) * 768 + g]; b = r1[(row0 - 63) * 768 + g]; }
    } else {
        int idx2  = idx - G2Z_OFF;
        int plane = idx2 / 24576;
        int rem   = idx2 % 24576;
        int pair  = rem >> 7;
        int col   = rem & 127;
        int g     = plane * 128 + col;
        int row0  = pair * 2;
        if (row0 < 256) { a = k2[row0 * 384 + g];         b = k2[(row0 + 1) * 384 + g]; }
        else            { a = r2[(row0 - 256) * 384 + g]; b = r2[(row0 - 255) * 384 + g]; }
    }
    __half2 h;
    h.x = __float2half_rn(a);
    h.y = __float2half_rn(b);
    ws[idx] = h;
}

// acc += w.lo * x0 + w.hi * x1   (fp16 weight, fp32 data/accum)
__device__ __forceinline__ void fma2(float& acc, __half2 w, float x0, float x1) {
    acc = fmaf(__half2float(__low2half(w)),  x0, acc);
    acc = fmaf(__half2float(__high2half(w)), x1, acc);
}

// Streamed K-segment: NPAIRS pairs, 3 gate planes, BLKP-deep register pipeline.
template <int COLS, int NPAIRS, int BLKP>
__device__ __forceinline__ void seg(const __half2* __restrict__ pz,
                                    const __half2* __restrict__ pr,
                                    const __half2* __restrict__ ph,
                                    const float* __restrict__ s0,
                                    float& az, float& ar, float& a3)
{
    constexpr int NB = NPAIRS / BLKP;
    __half2 bz[2][BLKP], br[2][BLKP], bh[2][BLKP];
    #pragma unroll
    for (int q = 0; q < BLKP; ++q) {
        bz[0][q] = pz[q * COLS]; br[0][q] = pr[q * COLS]; bh[0][q] = ph[q * COLS];
    }
    #pragma unroll
    for (int b = 0; b < NB; ++b) {
        const int cur = b & 1, nxt = cur ^ 1;
        if (b + 1 < NB) {
            const __half2* z2 = pz + (b + 1) * BLKP * COLS;
            const __half2* r2 = pr + (b + 1) * BLKP * COLS;
            const __half2* h2 = ph + (b + 1) * BLKP * COLS;
            #pragma unroll
            for (int q = 0; q < BLKP; ++q) {
                bz[nxt][q] = z2[q * COLS]; br[nxt][q] = r2[q * COLS]; bh[nxt][q] = h2[q * COLS];
            }
        }
        #pragma unroll
        for (int q = 0; q < BLKP; ++q) {
            const int i0 = (b * BLKP + q) * 2;
            const float2 v0 = *(const float2*)(s0 + i0);
            fma2(az, bz[cur][q], v0.x, v0.y);
            fma2(ar, br[cur][q], v0.x, v0.y);
            fma2(a3, bh[cur][q], v0.x, v0.y);
        }
    }
}

// 256 WGs x 512 threads, one batch row per WG. GRU1 recurrent weights live in
// registers (192 VGPRs/thread, loaded once); GRU1-x + GRU2 streamed from L2.
__global__ __launch_bounds__(512, 2)
void gru_fused(const float* __restrict__ x,
               const float* __restrict__ b1, const float* __restrict__ b2,
               const float* __restrict__ w3, const float* __restrict__ b3,
               const float* __restrict__ w4, const float* __restrict__ b4,
               const float* __restrict__ w5, const float* __restrict__ b5,
               const __half2* __restrict__ wp,
               float* __restrict__ out)
{
    __shared__ __align__(16) float h1[2][NU1];   // double-buffered
    __shared__ __align__(16) float h2[2][NU2];
    __shared__ __align__(16) float xt[2][FEAT];
    __shared__ float d3[64];
    __shared__ float d4[32];

    const int tid = threadIdx.x;
    const int row = blockIdx.x;
    const int j   = tid >> 1;       // GRU1 column
    const int kh  = tid & 1;        // GRU1 K-half
    const int c2  = tid >> 2;       // GRU2 column
    const int kq  = tid & 3;        // GRU2 K-quarter

    for (int i = tid; i < 2 * NU1; i += 512) (&h1[0][0])[i] = 0.0f;
    for (int i = tid; i < 2 * NU2; i += 512) (&h2[0][0])[i] = 0.0f;

    // biases masked to the lane that owns the reduction seed
    const float m1 = (kh == 0) ? 1.0f : 0.0f;
    const float bz1  = (b1[j] + b1[768 + j]) * m1;
    const float br1  = (b1[256 + j] + b1[1024 + j]) * m1;
    const float bxh1 = b1[512 + j] * m1;
    const float brh1 = b1[1280 + j] * m1;
    const float m2 = (kq == 0) ? 1.0f : 0.0f;
    const float bz2  = (b2[c2] + b2[384 + c2]) * m2;
    const float br2  = (b2[128 + c2] + b2[512 + c2]) * m2;
    const float bxh2 = b2[256 + c2] * m2;
    const float brh2 = b2[640 + c2] * m2;

    // column-offset plane pointers
    const __half2* g1z = wp + G1Z_OFF + j;
    const __half2* g1r = wp + G1R_OFF + j;
    const __half2* g1h = wp + G1H_OFF + j;

    // ---- register-resident GRU1 recurrent weights: pairs 32+kh*64+p ----
    // (pair 32+q covers h rows 2q,2q+1; lane kh owns h rows kh*128..kh*128+127)
    __half2 wz1[64], wr1[64], wh1[64];
    {
        const __half2* bzp = g1z + (32 + kh * 64) * 256;
        const __half2* brp = g1r + (32 + kh * 64) * 256;
        const __half2* bhp = g1h + (32 + kh * 64) * 256;
        #pragma unroll
        for (int p = 0; p < 64; ++p) {
            wz1[p] = bzp[p * 256]; wr1[p] = brp[p * 256]; wh1[p] = bhp[p * 256];
        }
    }
    // GRU1-x streamed pointers: FIXED — 16 pairs per lane (features kh*32..+31)
    const __half2* x1z = g1z + (kh * 16) * 256;
    const __half2* x1r = g1r + (kh * 16) * 256;
    const __half2* x1h = g1h + (kh * 16) * 256;
    // GRU2 streamed pointers: h1-part pairs kq*32+p; h2-part pairs 128+kq*16+p
    const __half2* g2zA = wp + G2Z_OFF + (kq * 32) * 128 + c2;
    const __half2* g2rA = wp + G2R_OFF + (kq * 32) * 128 + c2;
    const __half2* g2hA = wp + G2H_OFF + (kq * 32) * 128 + c2;
    const __half2* g2zB = wp + G2Z_OFF + (128 + kq * 16) * 128 + c2;
    const __half2* g2rB = wp + G2R_OFF + (128 + kq * 16) * 128 + c2;
    const __half2* g2hB = wp + G2H_OFF + (128 + kq * 16) * 128 + c2;

    if (tid < FEAT)
        xt[0][tid] = x[(size_t)row * TSEQ * FEAT + tid];
    __syncthreads();

    for (int t = 0; t < TSEQ; ++t) {
        const int cur = t & 1, nb = cur ^ 1;

        float xpre = 0.0f;
        if (t + 1 < TSEQ && tid < FEAT)
            xpre = x[(size_t)row * TSEQ * FEAT + (t + 1) * FEAT + tid];

        // ---------------- GRU1 ----------------
        float az = bz1, ar = br1, axh = bxh1, arh = brh1;
        // x-part: 16 pairs (features kh*32..kh*32+31), streamed
        seg<256, 16, 4>(x1z, x1r, x1h, &xt[cur][kh * 32], az, ar, axh);
        // h-part from registers (64 pairs), input via float4 LDS reads
        #pragma unroll
        for (int q = 0; q < 32; ++q) {
            const float4 v = *(const float4*)(&h1[cur][kh * 128 + q * 4]);
            fma2(az,  wz1[2 * q], v.x, v.y); fma2(az,  wz1[2 * q + 1], v.z, v.w);
            fma2(ar,  wr1[2 * q], v.x, v.y); fma2(ar,  wr1[2 * q + 1], v.z, v.w);
            fma2(arh, wh1[2 * q], v.x, v.y); fma2(arh, wh1[2 * q + 1], v.z, v.w);
        }
        // intra-wave K-half reduction (lanes 2m / 2m+1)
        az  += __shfl_xor(az, 1);
        ar  += __shfl_xor(ar, 1);
        axh += __shfl_xor(axh, 1);
        arh += __shfl_xor(arh, 1);
        {
            const float z  = sigmoid_f(az);
            const float rg = sigmoid_f(ar);
            const float hh = tanh_f(axh + rg * arh);
            const float hn = z * h1[cur][j] + (1.0f - z) * hh;
            if (kh == 0) h1[nb][j] = hn;
        }
        if (t + 1 < TSEQ && tid < FEAT) xt[nb][tid] = xpre;
        __syncthreads();   // the one barrier: h1[nb] + xt[nb] visible

        // ---------------- GRU2 (streamed, K-quarter per lane) ----------------
        float az2 = bz2, ar2 = br2, axh2 = bxh2, arh2 = brh2;
        seg<128, 32, 4>(g2zA, g2rA, g2hA, &h1[nb][kq * 64], az2, ar2, axh2);
        seg<128, 16, 4>(g2zB, g2rB, g2hB, &h2[cur][kq * 32], az2, ar2, arh2);
        az2  += __shfl_xor(az2, 1);  az2  += __shfl_xor(az2, 2);
        ar2  += __shfl_xor(ar2, 1);  ar2  += __shfl_xor(ar2, 2);
        axh2 += __shfl_xor(axh2, 1); axh2 += __shfl_xor(axh2, 2);
        arh2 += __shfl_xor(arh2, 1); arh2 += __shfl_xor(arh2, 2);
        {
            const float z2v = sigmoid_f(az2);
            const float rg2 = sigmoid_f(ar2);
            const float hh2 = tanh_f(axh2 + rg2 * arh2);
            const float hn2 = z2v * h2[cur][c2] + (1.0f - z2v) * hh2;
            if (kq == 0) h2[nb][c2] = hn2;
        }
        // no second barrier: next step's barrier covers h2[nb] visibility
    }
    __syncthreads();   // h2[0] (written at t=511) visible for the head

    // ---------------- dense head: h2[0] -> 64 -> 32 -> 24 ----------------
    if (tid < 64) {
        float a = b3[tid];
        #pragma unroll 4
        for (int u = 0; u < NU2; ++u) a += h2[0][u] * w3[u * 64 + tid];
        d3[tid] = a;
    }
    __syncthreads();
    if (tid < 32) {
        float a = b4[tid];
        #pragma unroll 4
        for (int u = 0; u < 64; ++u) a += d3[u] * w4[u * 32 + tid];
        d4[tid] = a;
    }
    __syncthreads();
    if (tid < 24) {
        float a = b5[tid];
        #pragma unroll 4
        for (int u = 0; u < 32; ++u) a += d4[u] * w5[u * 24 + tid];
        out[(size_t)row * 24 + tid] = a;
    }
}

extern "C" void kernel_launch(void* const* d_in, const int* in_sizes, int n_in,
                              void* d_out, int out_size, void* d_ws, size_t ws_size,
                              hipStream_t stream) {
    (void)in_sizes; (void)n_in; (void)ws_size; (void)out_size;
    const float* x  = (const float*)d_in[0];
    const float* k1 = (const float*)d_in[1];
    const float* r1 = (const float*)d_in[2];
    const float* b1 = (const float*)d_in[3];
    const float* k2 = (const float*)d_in[4];
    const float* r2 = (const float*)d_in[5];
    const float* b2 = (const float*)d_in[6];
    const float* w3 = (const float*)d_in[7];
    const float* b3 = (const float*)d_in[8];
    const float* w4 = (const float*)d_in[9];
    const float* b4 = (const float*)d_in[10];
    const float* w5 = (const float*)d_in[11];
    const float* b5 = (const float*)d_in[12];
    float* out = (float*)d_out;
    __half2* wp = (__half2*)d_ws;

    hipLaunchKernelGGL(pack_weights, dim3((TOTAL_H2 + 255) / 256), dim3(256), 0, stream,
                       k1, r1, k2, r2, wp);
    hipLaunchKernelGGL(gru_fused, dim3(BATCH), dim3(512), 0, stream,
                       x, b1, b2, w3, b3, w4, b4, w5, b5, wp, out);
}